// Round 4
// baseline (957.722 us; speedup 1.0000x reference)
//
#include <hip/hip_runtime.h>
#include <math.h>

// Problem constants: B=8, C=64, H=W=512, r=8
#define HW    262144      // 512*512 floats per plane
#define HW4   65536       // float4s per plane
#define NPLANE 512        // B*C planes
#define CH    64
#define HID   8           // C/r
#define IN2C  128         // 2C

// Native clang vector type — required by __builtin_nontemporal_store
// (HIP's float4 is a class and is rejected).
typedef float vfloat4 __attribute__((ext_vector_type(4)));

// ---------------- Kernel 1: per-plane mean + max reduction ----------------
// 512 blocks x 1024 threads = 2 blocks/CU, 32 waves/CU (full occupancy).
// Fully coalesced float4 loads. Normal (allocating) loads on purpose: they
// warm the 256 MiB Infinity Cache for the scale pass's re-read of x.
__global__ __launch_bounds__(1024) void reduce_kernel(const float* __restrict__ x,
                                                      float* __restrict__ avg_out,
                                                      float* __restrict__ max_out) {
    const int p = blockIdx.x;  // plane id (b*C + c), 0..511
    const vfloat4* xp = reinterpret_cast<const vfloat4*>(x) + (size_t)p * HW4;

    float s = 0.0f;
    float m = -INFINITY;
    // 65536 float4 / 1024 threads = 64 iterations, 16B/lane coalesced
    for (int i = threadIdx.x; i < HW4; i += 1024) {
        vfloat4 v = xp[i];
        s += (v.x + v.y) + (v.z + v.w);
        m = fmaxf(m, fmaxf(fmaxf(v.x, v.y), fmaxf(v.z, v.w)));
    }
    // wave-64 shuffle reduction
    #pragma unroll
    for (int off = 32; off > 0; off >>= 1) {
        s += __shfl_down(s, off, 64);
        m = fmaxf(m, __shfl_down(m, off, 64));
    }
    __shared__ float ls[16], lm[16];
    const int wave = threadIdx.x >> 6;
    const int lane = threadIdx.x & 63;
    if (lane == 0) { ls[wave] = s; lm[wave] = m; }
    __syncthreads();
    if (threadIdx.x == 0) {
        float ts = 0.0f, tm = -INFINITY;
        #pragma unroll
        for (int w = 0; w < 16; ++w) { ts += ls[w]; tm = fmaxf(tm, lm[w]); }
        avg_out[p] = ts * (1.0f / (float)HW);
        max_out[p] = tm;
    }
}

// ---------------- Kernel 2: fused gate-MLP + scale ----------------
// Each block owns a contiguous quarter-plane and recomputes its plane's gate
// from avg/max inline (~1K MACs, operands L2-resident) — removes the
// single-block MLP kernel and its two full-GPU drain bubbles.
//
// REVERSE block order: the reduce pass left the tail of x resident in L3;
// reading back-to-front turns that tail of the re-read into L3 hits.
// Non-temporal stores keep the zero-reuse output stream from evicting x.
__global__ __launch_bounds__(256) void scale_kernel(const float* __restrict__ x,
                                                    const float* __restrict__ avg_in,
                                                    const float* __restrict__ max_in,
                                                    const float* __restrict__ w1,  // [HID][IN2C]
                                                    const float* __restrict__ w2,  // [CH][HID]
                                                    float* __restrict__ out) {
    const int bi = (int)gridDim.x - 1 - (int)blockIdx.x;  // 2047..0
    const int plane = bi >> 2;            // 4 blocks per plane
    const int b = plane >> 6;             // batch
    const int c = plane & 63;             // channel

    // --- inline gate computation (block-redundant, negligible) ---
    __shared__ float h[HID];
    __shared__ float gsh;
    if (threadIdx.x < HID) {
        const float* w1r = w1 + threadIdx.x * IN2C;
        const float* av = avg_in + b * CH;
        const float* mx = max_in + b * CH;
        float acc = 0.0f;
        #pragma unroll 8
        for (int j = 0; j < CH; ++j) acc += av[j] * w1r[j];
        #pragma unroll 8
        for (int j = 0; j < CH; ++j) acc += mx[j] * w1r[CH + j];
        h[threadIdx.x] = acc >= 0.0f ? acc : 0.2f * acc;   // LeakyReLU(0.2)
    }
    __syncthreads();
    if (threadIdx.x == 0) {
        float acc = 0.0f;
        #pragma unroll
        for (int k = 0; k < HID; ++k) acc += h[k] * w2[c * HID + k];
        const float att = 1.0f / (1.0f + expf(-acc));
        gsh = att * 0.4f + 0.8f;
    }
    __syncthreads();
    const float g = gsh;

    // --- streaming scale, coalesced 16B/lane ---
    const size_t base = (size_t)bi * 16384;
    const vfloat4* x4 = reinterpret_cast<const vfloat4*>(x) + base;
    vfloat4* o4 = reinterpret_cast<vfloat4*>(out) + base;
    for (int i = threadIdx.x; i < 16384; i += 256) {
        vfloat4 v = x4[i];
        v *= g;
        __builtin_nontemporal_store(v, &o4[i]);
    }
}

extern "C" void kernel_launch(void* const* d_in, const int* in_sizes, int n_in,
                              void* d_out, int out_size, void* d_ws, size_t ws_size,
                              hipStream_t stream) {
    const float* x  = (const float*)d_in[0];   // [8,64,512,512] fp32
    const float* w1 = (const float*)d_in[1];   // [8,128]
    const float* w2 = (const float*)d_in[2];   // [64,8]
    float* out = (float*)d_out;
    float* ws  = (float*)d_ws;                 // fully overwritten before use
    float* avg = ws;          // 512
    float* mx  = ws + 512;    // 512

    reduce_kernel<<<NPLANE, 1024, 0, stream>>>(x, avg, mx);
    scale_kernel<<<2048, 256, 0, stream>>>(x, avg, mx, w1, w2, out);
}